// Round 5
// baseline (2499.292 us; speedup 1.0000x reference)
//
#include <hip/hip_runtime.h>
#include <cstdint>

// ElasticMHA on MI355X (gfx950). Inputs/outputs FLOAT32; internals bf16 MFMA.
// R5: attn histograms via ds_add_f32 (no shuffles), hoisted bias gather, LDS 36096 (4 blk/CU);
//     GEMMs all-bf16 with global_load_lds(16B) staging + XCD swizzle; q/k/v bf16 cvt prepass.

typedef unsigned short u16;
typedef unsigned int   u32;
typedef __attribute__((ext_vector_type(8))) __bf16 bf16x8;
typedef __attribute__((ext_vector_type(4))) float  f32x4;

#define B_   32
#define L_   577
#define D_   768
#define H_   12
#define HD_  64
#define LP_  640            // padded rows per (b,h): 10 Q-tiles of 64
#define M_   (B_*L_)        // 18464
#define SCALE_ 0.125f

__device__ __forceinline__ float b2f(u16 u){ u32 x = ((u32)u) << 16; float f; __builtin_memcpy(&f,&x,4); return f; }
__device__ __forceinline__ u16 f2b(float f){ u32 x; __builtin_memcpy(&x,&f,4); u32 r = (x + 0x7FFFu + ((x>>16)&1u)) >> 16; return (u16)r; }

__device__ __forceinline__ f32x4 mfma_bf16(bf16x8 a, bf16x8 b, f32x4 c){
  return __builtin_amdgcn_mfma_f32_16x16x32_bf16(a, b, c, 0, 0, 0);
}

// async global->LDS, 16B/lane; LDS dest = wave-uniform base + lane*16 (m97/m104)
__device__ __forceinline__ void async16(const void* g, void* l){
  __builtin_amdgcn_global_load_lds(
    (const __attribute__((address_space(1))) void*)g,
    (__attribute__((address_space(3))) void*)l,
    16, 0, 0);
}

__device__ __forceinline__ void lds_fence(){
  asm volatile("s_waitcnt lgkmcnt(0)" ::: "memory");
}

// dot of 64 bf16 (qrow) with 64 f32 (trow)
__device__ __forceinline__ float dotqt(const u16* qrow, const float* trow){
  float s = 0.f;
  #pragma unroll
  for (int u2 = 0; u2 < 8; ++u2){
    uint4  a  = *(const uint4*)(qrow + u2*8);
    float4 t0 = *(const float4*)(trow + u2*8);
    float4 t1 = *(const float4*)(trow + u2*8 + 4);
    u32 aa[4] = {a.x, a.y, a.z, a.w};
    float tt[8] = {t0.x,t0.y,t0.z,t0.w,t1.x,t1.y,t1.z,t1.w};
    #pragma unroll
    for (int e = 0; e < 4; ++e){
      s += b2f((u16)(aa[e] & 0xffffu)) * tt[2*e];
      s += b2f((u16)(aa[e] >> 16))     * tt[2*e+1];
    }
  }
  return s;
}

// ---------------- q/k/v f32 -> bf16 cvt prepass ----------------
__global__ __launch_bounds__(256) void cvt3_bf16(
    const float* __restrict__ q, const float* __restrict__ k, const float* __restrict__ v,
    u16* __restrict__ dq, u16* __restrict__ dk, u16* __restrict__ dv)
{
  int z = blockIdx.y;
  const float* s = (z==0)?q:(z==1)?k:v;
  u16*         d = (z==0)?dq:(z==1)?dk:dv;
  int i = blockIdx.x*256 + threadIdx.x;          // uint4 (8 elem) index
  if (i >= (M_*D_)/8) return;
  const float4* s4 = (const float4*)s;
  float4 a = s4[2*i], b = s4[2*i+1];
  uint4 o;
  o.x = (u32)f2b(a.x) | ((u32)f2b(a.y)<<16);
  o.y = (u32)f2b(a.z) | ((u32)f2b(a.w)<<16);
  o.z = (u32)f2b(b.x) | ((u32)f2b(b.y)<<16);
  o.w = (u32)f2b(b.z) | ((u32)f2b(b.w)<<16);
  ((uint4*)d)[i] = o;
}

// ---------------- weight transpose+cvt: WT[n][k] = bf16(W[k][n]) ----------------
__global__ __launch_bounds__(256) void transpose768(
    const float* __restrict__ W0, const float* __restrict__ W1,
    const float* __restrict__ W2, const float* __restrict__ W3,
    u16* __restrict__ T0, u16* __restrict__ T1, u16* __restrict__ T2, u16* __restrict__ T3)
{
  __shared__ float t[32][33];
  int z = blockIdx.z;
  const float* W = (z==0)?W0:(z==1)?W1:(z==2)?W2:W3;
  u16*         T = (z==0)?T0:(z==1)?T1:(z==2)?T2:T3;
  int kb = blockIdx.x*32, nb = blockIdx.y*32;
  int tx = threadIdx.x & 31, ty = threadIdx.x >> 5;   // 32 x 8
  #pragma unroll
  for (int r=0;r<32;r+=8) t[ty+r][tx] = W[(size_t)(kb+ty+r)*768 + nb+tx];
  __syncthreads();
  #pragma unroll
  for (int r=0;r<32;r+=8) T[(size_t)(nb+ty+r)*768 + kb+tx] = f2b(t[tx][ty+r]);
}

// ---------------- 128x128 MFMA GEMM, m97 staging, XCD swizzle ----------------
// mode 0..2: A = bf16 [M,768], Dst = bf16 head layout [B,H,LP,64] (+bias)
// mode 3   : A = bf16 oh head layout, Dst = f32 out [M,768] (+bias+residual)
// grid: 912 blocks; blocks with same m-tile land on same XCD (b%8) -> A fetched once.
__global__ __launch_bounds__(256) void gemm_kernel(
    const u16* __restrict__ A, const u16* __restrict__ BT,
    const float* __restrict__ bias, const float* __restrict__ resid,
    void* __restrict__ Dstv, int mode)
{
  __shared__ __align__(16) u16 AsL[128*32];
  __shared__ __align__(16) u16 BsL[128*32];
  const int blk = blockIdx.x;
  const int x = blk & 7, g = blk >> 3;       // XCD-slot, work id
  const int n0 = (g % 6) * 128;
  const int m_idx = (g / 6) * 8 + x;
  if (m_idx >= 145) return;
  const int m0 = m_idx * 128;

  const int tid = threadIdx.x;
  const int w = tid>>6, lane = tid&63, q = lane>>4, c = lane&15;
  const int wr = w>>1, wc = w&1;

  f32x4 acc[4][4];
  #pragma unroll
  for (int ai=0;ai<4;++ai)
    #pragma unroll
    for (int bi=0;bi<4;++bi){ f32x4 z = {0.f,0.f,0.f,0.f}; acc[ai][bi] = z; }

  for (int k0 = 0; k0 < 768; k0 += 32){
    __syncthreads();
    #pragma unroll
    for (int t2 = 0; t2 < 2; ++t2){
      int idx = t2*256 + tid;
      int row = idx >> 2, ch = idx & 3;
      int mrow = m0 + row; if (mrow > M_-1) mrow = M_-1;
      const u16* srcA;
      if (mode < 3) srcA = A + (size_t)mrow*768 + k0 + ch*8;
      else {
        int bb = mrow / L_, ll = mrow - bb*L_;
        int hh = k0 >> 6, dd = (k0 & 63) + ch*8;
        srcA = A + (((size_t)(bb*H_ + hh)*LP_ + ll) << 6) + dd;
      }
      async16(srcA, (char*)AsL + (size_t)(t2*256 + w*64)*16);
      async16(BT + (size_t)(n0 + row)*768 + k0 + ch*8, (char*)BsL + (size_t)(t2*256 + w*64)*16);
    }
    __syncthreads();   // vmcnt(0) drain inserted by compiler (m97)

    bf16x8 af[4], bf2[4];
    #pragma unroll
    for (int ai=0;ai<4;++ai) af[ai]  = *(const bf16x8*)&AsL[(wr*64 + ai*16 + c)*32 + q*8];
    #pragma unroll
    for (int bi=0;bi<4;++bi) bf2[bi] = *(const bf16x8*)&BsL[(wc*64 + bi*16 + c)*32 + q*8];
    #pragma unroll
    for (int ai=0;ai<4;++ai)
      #pragma unroll
      for (int bi=0;bi<4;++bi)
        acc[ai][bi] = mfma_bf16(af[ai], bf2[bi], acc[ai][bi]);
  }

  // epilogue: C layout row = q*4+reg, col = lane&15 (m89)
  #pragma unroll
  for (int ai=0;ai<4;++ai){
    #pragma unroll
    for (int r2=0;r2<4;++r2){
      int mrow = m0 + wr*64 + ai*16 + q*4 + r2;
      if (mrow >= M_) continue;
      int bb = mrow / L_;
      int ll = mrow - bb*L_;
      #pragma unroll
      for (int bi=0;bi<4;++bi){
        int col = n0 + wc*64 + bi*16 + c;
        float vv = acc[ai][bi][r2] + bias[col];
        if (mode < 3){
          int hh = col >> 6, dd = col & 63;
          ((u16*)Dstv)[(((size_t)(bb*H_ + hh)*LP_ + ll) << 6) + dd] = f2b(vv);
        } else {
          size_t o2 = (size_t)mrow*768 + col;
          ((float*)Dstv)[o2] = vv + resid[o2];
        }
      }
    }
  }
}

// ---------------- fused attention ----------------
// 256 thr (4 waves), 64 Q rows of one (b,h); 19 x 32-col j-tiles.
// LDS: Ks[32][72]u16 | Vts[64][40]u16 | Ps[4][16][40]u16 | pvhb[64][66]bf16 | gvh[64][50]f32
__global__ __launch_bounds__(256) void attn_kernel(
    const u16* __restrict__ qh, const u16* __restrict__ kh, const u16* __restrict__ vh,
    const float* __restrict__ tvk, const float* __restrict__ thk,
    const float* __restrict__ tvv, const float* __restrict__ thv,
    u16* __restrict__ oh)
{
  __shared__ __align__(16) char sb[36096];
  u16*   Ks   = (u16*)sb;                 // 4608 B
  u16*   Vts  = (u16*)(sb + 4608);        // 5120 B
  u16*   Ps   = (u16*)(sb + 9728);        // 5120 B
  u16*   pvhb = (u16*)(sb + 14848);       // 8448 B : [row][66] bf16, bins 0..59 (v 0..29, h 30..59)
  float* gvh  = (float*)(sb + 23296);     // 12800 B: [row][50] gv:0..24(24=CLS) gh:25..49(49=CLS)
  // fold-phase overlays: Wm at sb+0 (9216 B), tabT at sb+9728 (9216 B)

  const int tid = threadIdx.x;
  const int w = tid>>6, lane = tid&63, q = lane>>4, c = lane&15;
  const int qt = blockIdx.x, h = blockIdx.y, b = blockIdx.z;
  const int i0 = qt * 64;
  const size_t bh = (size_t)(b*H_ + h) * LP_ * HD_;
  const u16* qh_b = qh + bh;
  const u16* kh_b = kh + bh;
  const u16* vh_b = vh + bh;

  // phase 0: zero histograms, compute bias tables pvhb for this block's 64 rows
  for (int o = tid; o < 64*50; o += 256) gvh[o] = 0.f;
  for (int o = tid; o < 64*60; o += 256){
    int row = o / 60, bin = o - (o/60)*60;
    const u16* qrow = qh_b + (size_t)(i0 + row) * HD_;
    const float* trow = (bin < 30) ? (tvk + bin*HD_) : (thk + (bin-30)*HD_);
    pvhb[row*66 + bin] = f2b(dotqt(qrow, trow));
  }

  // per-lane row constants (C layout rows: q*4+r)
  int rv_[4], cv_[4], ig_[4];
  #pragma unroll
  for (int r=0;r<4;++r){
    int ig = i0 + w*16 + q*4 + r;
    ig_[r] = ig;
    int ii = ig > 0 ? ig - 1 : 0;
    int dv24 = ii / 24;
    rv_[r] = dv24;
    cv_[r] = ii - dv24*24;
  }

  // Q fragments (A layout: m=lane&15, k=q*8+j, two k-halves)
  bf16x8 aq0 = *(const bf16x8*)(qh_b + (size_t)(i0 + w*16 + c)*HD_ + q*8);
  bf16x8 aq1 = *(const bf16x8*)(qh_b + (size_t)(i0 + w*16 + c)*HD_ + 32 + q*8);

  f32x4 o4[4];
  #pragma unroll
  for (int nt=0;nt<4;++nt){ f32x4 z = {0.f,0.f,0.f,0.f}; o4[nt] = z; }
  float lsum[4] = {0.f,0.f,0.f,0.f};
  u16* Ps_w = Ps + w*(16*40);

  __syncthreads();

  // CLS-slot bias values per r (pvhb bins 0 and 30), loaded once
  float pv0[4], ph0[4];
  #pragma unroll
  for (int r=0;r<4;++r){
    int lrow = w*16 + q*4 + r;
    pv0[r] = b2f(pvhb[lrow*66 + 0]);
    ph0[r] = b2f(pvhb[lrow*66 + 30]);
  }

  for (int jt = 0; jt < 19; ++jt){
    int j0 = jt * 32;
    __syncthreads();
    { // stage K tile [32][72] and V^T tile [64][40]
      int row = tid >> 3, ch = tid & 7;
      uint4 d4 = *(const uint4*)(kh_b + (size_t)(j0+row)*HD_ + ch*8);
      *(uint4*)(Ks + row*72 + ch*8) = d4;
      int jl = tid & 31, dch = (tid >> 5) * 8;
      uint4 v4 = *(const uint4*)(vh_b + (size_t)(j0+jl)*HD_ + dch);
      u32 vvv[4] = {v4.x, v4.y, v4.z, v4.w};
      #pragma unroll
      for (int e=0;e<4;++e){
        Vts[(dch + 2*e    )*40 + jl] = (u16)(vvv[e] & 0xffffu);
        Vts[(dch + 2*e + 1)*40 + jl] = (u16)(vvv[e] >> 16);
      }
    }
    __syncthreads();

    #pragma unroll
    for (int sub=0; sub<2; ++sub){
      bf16x8 bk0 = *(const bf16x8*)(Ks + (sub*16 + c)*72 + q*8);
      bf16x8 bk1 = *(const bf16x8*)(Ks + (sub*16 + c)*72 + 32 + q*8);
      f32x4 s4 = {0.f,0.f,0.f,0.f};
      s4 = mfma_bf16(aq0, bk0, s4);
      s4 = mfma_bf16(aq1, bk1, s4);

      int jbase = j0 + sub*16;
      int j  = jbase + c;
      bool jv = (j < L_);
      int jj = j - 1;
      int gR  = (j==0) ? 24 : (jj/24);  if (gR > 23 && j != 0) gR = 23;   // gv bin
      int cbR = (j==0) ? 24 : (jj - (jj/24)*24);                          // gh bin
      // sub-uniform g bounds for hoisted v-bias
      int sga = (jbase <= 1) ? 0 : ((jbase-1)/24); if (sga > 23) sga = 23;
      int sgb = (jbase + 14) / 24;                 if (sgb > 23) sgb = 23;

      #pragma unroll
      for (int r=0;r<4;++r){
        int lrow = w*16 + q*4 + r;
        // hoisted v-bias: <=2 distinct g per subtile
        int dvlo = sga - rv_[r]; dvlo = dvlo < -14 ? -14 : (dvlo > 14 ? 14 : dvlo);
        int dvhi = sgb - rv_[r]; dvhi = dvhi < -14 ? -14 : (dvhi > 14 ? 14 : dvhi);
        float bvlo = b2f(pvhb[lrow*66 + dvlo + 15]);
        float bvhi = b2f(pvhb[lrow*66 + dvhi + 15]);
        float bv = (gR == sgb) ? bvhi : bvlo;
        int dh = cbR - cv_[r]; dh = dh < -14 ? -14 : (dh > 14 ? 14 : dh);
        float bhh = b2f(pvhb[lrow*66 + dh + 45]);
        bool cls = (j == 0) || (ig_[r] == 0);
        float bias = (cls ? pv0[r] : bv) + (cls ? ph0[r] : bhh);
        float s = s4[r]*SCALE_ + bias;
        s = fminf(fmaxf(s, -80.f), 30.f);           // NaN-proof clamp
        float p = jv ? __expf(s) : 0.f;             // no-max softmax
        lsum[r] += p;
        Ps_w[(q*4+r)*40 + sub*16 + c] = f2b(p);
        atomicAdd(&gvh[lrow*50 + gR], p);           // ds_add_f32
        atomicAdd(&gvh[lrow*50 + 25 + cbR], p);
      }
    }
    // P·V via LDS round-trip (m120); fence stops TBAA reordering of bf16 read vs u16 write
    lds_fence();
    bf16x8 ap = *(const bf16x8*)(Ps_w + c*40 + q*8);
    #pragma unroll
    for (int nt=0;nt<4;++nt){
      bf16x8 bv2 = *(const bf16x8*)(Vts + (nt*16 + c)*40 + q*8);
      o4[nt] = mfma_bf16(ap, bv2, o4[nt]);
    }
  }

  __syncthreads();   // all ds_adds drained; Ks/Vts/Ps/pvhb dead

  // fold histograms into table-space weights W[16 rows][72-padded bins] bf16 (overlay Ks/Vts)
  u16* Wm = (u16*)sb + w*(16*72);
  for (int o = lane; o < 16*72; o += 64) Wm[o] = 0;
  if (lane < 16){
    int lrow = w*16 + lane;
    int ig = i0 + lrow;
    const float* gv = gvh + lrow*50;
    u16* wrp = Wm + lane*72;
    if (ig == 0){
      float sv=0.f, sh=0.f;
      for (int g2=0; g2<25; ++g2){ sv += gv[g2]; sh += gv[25+g2]; }
      wrp[0] = f2b(sv); wrp[30] = f2b(sh);
    } else {
      int rr = (ig-1)/24, cc2 = (ig-1) - ((ig-1)/24)*24;
      wrp[0]  = f2b(gv[24]);     // CLS -> table idx 0
      wrp[30] = f2b(gv[49]);
      for (int t=1; t<30; ++t){
        float sv = 0.f, sh = 0.f;
        if (t == 1){
          for (int g2=0; g2 <= rr-14  && g2 < 24; ++g2) sv += gv[g2];
          for (int c2=0; c2 <= cc2-14 && c2 < 24; ++c2) sh += gv[25+c2];
        } else if (t == 29){
          for (int g2 = (rr+14  < 0 ? 0 : rr+14 ); g2 < 24; ++g2) sv += gv[g2];
          for (int c2 = (cc2+14 < 0 ? 0 : cc2+14); c2 < 24; ++c2) sh += gv[25+c2];
        } else {
          int g2 = rr  + t - 15; if (g2 >= 0 && g2 < 24) sv = gv[g2];
          int c2 = cc2 + t - 15; if (c2 >= 0 && c2 < 24) sh = gv[25+c2];
        }
        wrp[t] = f2b(sv); wrp[30+t] = f2b(sh);
      }
    }
  }
  // combined value-table transposed: tabT[d][bin] (overlay Ps+pvhb)
  u16* tabT = (u16*)(sb + 9728);
  for (int o = tid; o < 64*72; o += 256){
    int d2 = o / 72, b2 = o - (o/72)*72;
    float val = 0.f;
    if (b2 < 30)      val = tvv[b2*HD_ + d2];
    else if (b2 < 60) val = thv[(b2-30)*HD_ + d2];
    tabT[d2*72 + b2] = f2b(val);
  }
  __syncthreads();

  // rel-V term: o += W(16x64) @ TabC(64x64) — C layout aligned with o4
  bf16x8 aw0 = *(const bf16x8*)(Wm + c*72 + q*8);
  bf16x8 aw1 = *(const bf16x8*)(Wm + c*72 + 32 + q*8);
  #pragma unroll
  for (int nt=0;nt<4;++nt){
    bf16x8 bt0 = *(const bf16x8*)(tabT + (nt*16+c)*72 + q*8);
    bf16x8 bt1 = *(const bf16x8*)(tabT + (nt*16+c)*72 + 32 + q*8);
    o4[nt] = mfma_bf16(aw0, bt0, o4[nt]);
    o4[nt] = mfma_bf16(aw1, bt1, o4[nt]);
  }

  // softmax denominator + store
  #pragma unroll
  for (int r=0;r<4;++r){
    #pragma unroll
    for (int off=1; off<16; off<<=1) lsum[r] += __shfl_xor(lsum[r], off);
  }
  u16* oh_b = oh + bh;
  #pragma unroll
  for (int r=0;r<4;++r){
    if (ig_[r] < L_){
      float inv = 1.f / lsum[r];
      #pragma unroll
      for (int nt=0;nt<4;++nt)
        oh_b[(size_t)ig_[r]*HD_ + nt*16 + c] = f2b(o4[nt][r] * inv);
    }
  }
}

// ---------------- launch ----------------
extern "C" void kernel_launch(void* const* d_in, const int* in_sizes, int n_in,
                              void* d_out, int out_size, void* d_ws, size_t ws_size,
                              hipStream_t stream)
{
  (void)in_sizes; (void)n_in; (void)out_size; (void)ws_size;
  const float* q_   = (const float*)d_in[0];
  const float* k_   = (const float*)d_in[1];
  const float* v_   = (const float*)d_in[2];
  const float* Wq_  = (const float*)d_in[3];
  const float* bq_  = (const float*)d_in[4];
  const float* Wk_  = (const float*)d_in[5];
  const float* bk_  = (const float*)d_in[6];
  const float* Wv_  = (const float*)d_in[7];
  const float* bv_  = (const float*)d_in[8];
  const float* Wp_  = (const float*)d_in[9];
  const float* bp_  = (const float*)d_in[10];
  const float* tvk_ = (const float*)d_in[11];
  const float* thk_ = (const float*)d_in[12];
  const float* tvv_ = (const float*)d_in[13];
  const float* thv_ = (const float*)d_in[14];

  char* ws = (char*)d_ws;
  const size_t szHead = (size_t)B_*H_*LP_*HD_*2;   // 31,457,280 B
  const size_t szQKV  = (size_t)M_*D_*2;           // 28,360,704 B
  u16* qh   = (u16*)(ws);
  u16* kh   = (u16*)(ws + szHead);
  u16* vh   = (u16*)(ws + 2*szHead);
  u16* oh   = (u16*)(ws + 3*szHead);   // doubles as q_bf before attn (q_bf dead once qh exists)
  u16* q_bf = oh;
  u16* k_bf = (u16*)(ws + 4*szHead);
  u16* v_bf = (u16*)(ws + 4*szHead + szQKV);
  u16* WqT  = (u16*)(ws + 4*szHead + 2*szQKV);
  u16* WkT  = WqT + 768*768;
  u16* WvT  = WkT + 768*768;
  u16* WpT  = WvT + 768*768;
  // total ~187.3 MB

  transpose768<<<dim3(24,24,4), 256, 0, stream>>>(Wq_, Wk_, Wv_, Wp_, WqT, WkT, WvT, WpT);
  cvt3_bf16<<<dim3((M_*D_/8 + 255)/256, 3), 256, 0, stream>>>(q_, k_, v_, q_bf, k_bf, v_bf);
  gemm_kernel<<<912, 256, 0, stream>>>(q_bf, WqT, bq_, nullptr, qh, 0);
  gemm_kernel<<<912, 256, 0, stream>>>(k_bf, WkT, bk_, nullptr, kh, 1);
  gemm_kernel<<<912, 256, 0, stream>>>(v_bf, WvT, bv_, nullptr, vh, 2);
  attn_kernel<<<dim3(10,12,32), 256, 0, stream>>>(qh, kh, vh, tvk_, thk_, tvv_, thv_, oh);
  gemm_kernel<<<912, 256, 0, stream>>>(oh, WpT, bp_, q_, d_out, 3);
}

// Round 6
// 1187.549 us; speedup vs baseline: 2.1046x; 2.1046x over previous
//
#include <hip/hip_runtime.h>
#include <cstdint>

// ElasticMHA on MI355X (gfx950). Inputs/outputs FLOAT32; internals bf16 MFMA.
// R6: attn histograms computed by MFMA against precomputed 0/1 indicator fragments
//     (kills R5's contended ds_add_f32 and R4's shuffle block); softmax denom from
//     histogram row-sums. GEMMs unchanged from R5 (async16 m97 staging + XCD swizzle).

typedef unsigned short u16;
typedef unsigned int   u32;
typedef __attribute__((ext_vector_type(8))) __bf16 bf16x8;
typedef __attribute__((ext_vector_type(4))) float  f32x4;

#define B_   32
#define L_   577
#define D_   768
#define H_   12
#define HD_  64
#define LP_  640            // padded rows per (b,h): 10 Q-tiles of 64
#define M_   (B_*L_)        // 18464
#define SCALE_ 0.125f

__device__ __forceinline__ float b2f(u16 u){ u32 x = ((u32)u) << 16; float f; __builtin_memcpy(&f,&x,4); return f; }
__device__ __forceinline__ u16 f2b(float f){ u32 x; __builtin_memcpy(&x,&f,4); u32 r = (x + 0x7FFFu + ((x>>16)&1u)) >> 16; return (u16)r; }

__device__ __forceinline__ f32x4 mfma_bf16(bf16x8 a, bf16x8 b, f32x4 c){
  return __builtin_amdgcn_mfma_f32_16x16x32_bf16(a, b, c, 0, 0, 0);
}

// async global->LDS, 16B/lane; LDS dest = wave-uniform base + lane*16 (m97/m104)
__device__ __forceinline__ void async16(const void* g, void* l){
  __builtin_amdgcn_global_load_lds(
    (const __attribute__((address_space(1))) void*)g,
    (__attribute__((address_space(3))) void*)l,
    16, 0, 0);
}

__device__ __forceinline__ void lds_fence(){
  asm volatile("s_waitcnt lgkmcnt(0)" ::: "memory");
}

// dot of 64 bf16 (qrow) with 64 f32 (trow)
__device__ __forceinline__ float dotqt(const u16* qrow, const float* trow){
  float s = 0.f;
  #pragma unroll
  for (int u2 = 0; u2 < 8; ++u2){
    uint4  a  = *(const uint4*)(qrow + u2*8);
    float4 t0 = *(const float4*)(trow + u2*8);
    float4 t1 = *(const float4*)(trow + u2*8 + 4);
    u32 aa[4] = {a.x, a.y, a.z, a.w};
    float tt[8] = {t0.x,t0.y,t0.z,t0.w,t1.x,t1.y,t1.z,t1.w};
    #pragma unroll
    for (int e = 0; e < 4; ++e){
      s += b2f((u16)(aa[e] & 0xffffu)) * tt[2*e];
      s += b2f((u16)(aa[e] >> 16))     * tt[2*e+1];
    }
  }
  return s;
}

// ---------------- indicator fragments for histogram MFMA ----------------
// ind[jt][nt][lane][idx]: B-fragment element Ind[k = (lane>>4)*8+idx][n = nt*16+(lane&15)]
// for j = jt*32+k. bins: n<25 -> gv (g==n), 25<=n<50 -> gh (cb==n-25), else 0.
__global__ __launch_bounds__(256) void ind_setup(u16* __restrict__ ind)
{
  int jt = blockIdx.x;
  int t  = threadIdx.x;
  int nt = t >> 6, lane = t & 63;
  int qq = lane >> 4, cc = lane & 15;
  int n = nt*16 + cc;
  u16 vals[8];
  #pragma unroll
  for (int idx = 0; idx < 8; ++idx){
    int j = jt*32 + qq*8 + idx;
    int bv, bhh;
    if (j == 0){ bv = 24; bhh = 24; }
    else { int jj = j-1; bv = jj/24; if (bv > 23) bv = 23; bhh = jj - (jj/24)*24; }
    bool one = (n < 25) ? (bv == n) : ((n < 50) ? (bhh == n-25) : false);
    vals[idx] = one ? (u16)0x3F80 : (u16)0;
  }
  *(uint4*)&ind[(size_t)((jt*4 + nt)*64 + lane)*8] = *(uint4*)vals;
}

// ---------------- q/k/v f32 -> bf16 cvt prepass ----------------
__global__ __launch_bounds__(256) void cvt3_bf16(
    const float* __restrict__ q, const float* __restrict__ k, const float* __restrict__ v,
    u16* __restrict__ dq, u16* __restrict__ dk, u16* __restrict__ dv)
{
  int z = blockIdx.y;
  const float* s = (z==0)?q:(z==1)?k:v;
  u16*         d = (z==0)?dq:(z==1)?dk:dv;
  int i = blockIdx.x*256 + threadIdx.x;          // uint4 (8 elem) index
  if (i >= (M_*D_)/8) return;
  const float4* s4 = (const float4*)s;
  float4 a = s4[2*i], b = s4[2*i+1];
  uint4 o;
  o.x = (u32)f2b(a.x) | ((u32)f2b(a.y)<<16);
  o.y = (u32)f2b(a.z) | ((u32)f2b(a.w)<<16);
  o.z = (u32)f2b(b.x) | ((u32)f2b(b.y)<<16);
  o.w = (u32)f2b(b.z) | ((u32)f2b(b.w)<<16);
  ((uint4*)d)[i] = o;
}

// ---------------- weight transpose+cvt: WT[n][k] = bf16(W[k][n]) ----------------
__global__ __launch_bounds__(256) void transpose768(
    const float* __restrict__ W0, const float* __restrict__ W1,
    const float* __restrict__ W2, const float* __restrict__ W3,
    u16* __restrict__ T0, u16* __restrict__ T1, u16* __restrict__ T2, u16* __restrict__ T3)
{
  __shared__ float t[32][33];
  int z = blockIdx.z;
  const float* W = (z==0)?W0:(z==1)?W1:(z==2)?W2:W3;
  u16*         T = (z==0)?T0:(z==1)?T1:(z==2)?T2:T3;
  int kb = blockIdx.x*32, nb = blockIdx.y*32;
  int tx = threadIdx.x & 31, ty = threadIdx.x >> 5;   // 32 x 8
  #pragma unroll
  for (int r=0;r<32;r+=8) t[ty+r][tx] = W[(size_t)(kb+ty+r)*768 + nb+tx];
  __syncthreads();
  #pragma unroll
  for (int r=0;r<32;r+=8) T[(size_t)(nb+ty+r)*768 + kb+tx] = f2b(t[tx][ty+r]);
}

// ---------------- 128x128 MFMA GEMM, m97 staging, XCD swizzle ----------------
// mode 0..2: A = bf16 [M,768], Dst = bf16 head layout [B,H,LP,64] (+bias)
// mode 3   : A = bf16 oh head layout, Dst = f32 out [M,768] (+bias+residual)
__global__ __launch_bounds__(256) void gemm_kernel(
    const u16* __restrict__ A, const u16* __restrict__ BT,
    const float* __restrict__ bias, const float* __restrict__ resid,
    void* __restrict__ Dstv, int mode)
{
  __shared__ __align__(16) u16 AsL[128*32];
  __shared__ __align__(16) u16 BsL[128*32];
  const int blk = blockIdx.x;
  const int x = blk & 7, g = blk >> 3;       // XCD-slot, work id
  const int n0 = (g % 6) * 128;
  const int m_idx = (g / 6) * 8 + x;
  if (m_idx >= 145) return;
  const int m0 = m_idx * 128;

  const int tid = threadIdx.x;
  const int w = tid>>6, lane = tid&63, q = lane>>4, c = lane&15;
  const int wr = w>>1, wc = w&1;

  f32x4 acc[4][4];
  #pragma unroll
  for (int ai=0;ai<4;++ai)
    #pragma unroll
    for (int bi=0;bi<4;++bi){ f32x4 z = {0.f,0.f,0.f,0.f}; acc[ai][bi] = z; }

  for (int k0 = 0; k0 < 768; k0 += 32){
    __syncthreads();
    #pragma unroll
    for (int t2 = 0; t2 < 2; ++t2){
      int idx = t2*256 + tid;
      int row = idx >> 2, ch = idx & 3;
      int mrow = m0 + row; if (mrow > M_-1) mrow = M_-1;
      const u16* srcA;
      if (mode < 3) srcA = A + (size_t)mrow*768 + k0 + ch*8;
      else {
        int bb = mrow / L_, ll = mrow - bb*L_;
        int hh = k0 >> 6, dd = (k0 & 63) + ch*8;
        srcA = A + (((size_t)(bb*H_ + hh)*LP_ + ll) << 6) + dd;
      }
      async16(srcA, (char*)AsL + (size_t)(t2*256 + w*64)*16);
      async16(BT + (size_t)(n0 + row)*768 + k0 + ch*8, (char*)BsL + (size_t)(t2*256 + w*64)*16);
    }
    __syncthreads();

    bf16x8 af[4], bf2[4];
    #pragma unroll
    for (int ai=0;ai<4;++ai) af[ai]  = *(const bf16x8*)&AsL[(wr*64 + ai*16 + c)*32 + q*8];
    #pragma unroll
    for (int bi=0;bi<4;++bi) bf2[bi] = *(const bf16x8*)&BsL[(wc*64 + bi*16 + c)*32 + q*8];
    #pragma unroll
    for (int ai=0;ai<4;++ai)
      #pragma unroll
      for (int bi=0;bi<4;++bi)
        acc[ai][bi] = mfma_bf16(af[ai], bf2[bi], acc[ai][bi]);
  }

  // epilogue: C layout row = q*4+reg, col = lane&15 (m89)
  #pragma unroll
  for (int ai=0;ai<4;++ai){
    #pragma unroll
    for (int r2=0;r2<4;++r2){
      int mrow = m0 + wr*64 + ai*16 + q*4 + r2;
      if (mrow >= M_) continue;
      int bb = mrow / L_;
      int ll = mrow - bb*L_;
      #pragma unroll
      for (int bi=0;bi<4;++bi){
        int col = n0 + wc*64 + bi*16 + c;
        float vv = acc[ai][bi][r2] + bias[col];
        if (mode < 3){
          int hh = col >> 6, dd = col & 63;
          ((u16*)Dstv)[(((size_t)(bb*H_ + hh)*LP_ + ll) << 6) + dd] = f2b(vv);
        } else {
          size_t o2 = (size_t)mrow*768 + col;
          ((float*)Dstv)[o2] = vv + resid[o2];
        }
      }
    }
  }
}

// ---------------- fused attention ----------------
// 256 thr (4 waves), 64 Q rows of one (b,h); 19 x 32-col j-tiles.
// LDS: Ks[32][72]u16 | Vts[64][40]u16 | Ps[4][16][40]u16 | pvhb[64][66]bf16 | gvh[64][52]f32
__global__ __launch_bounds__(256) void attn_kernel(
    const u16* __restrict__ qh, const u16* __restrict__ kh, const u16* __restrict__ vh,
    const float* __restrict__ tvk, const float* __restrict__ thk,
    const float* __restrict__ tvv, const float* __restrict__ thv,
    const u16* __restrict__ ind,
    u16* __restrict__ oh)
{
  __shared__ __align__(16) char sb[36608];
  u16*   Ks   = (u16*)sb;                 // 4608 B
  u16*   Vts  = (u16*)(sb + 4608);        // 5120 B
  u16*   Ps   = (u16*)(sb + 9728);        // 5120 B
  u16*   pvhb = (u16*)(sb + 14848);       // 8448 B : [row][66] bf16, bins 0..59
  float* gvh  = (float*)(sb + 23296);     // 13312 B: [row][52] gv:0..24(24=CLS) gh:25..49(49=CLS)
  // fold overlays: Wm at sb+0 (9216 B), tabT at sb+9728 (9216 B)

  const int tid = threadIdx.x;
  const int w = tid>>6, lane = tid&63, q = lane>>4, c = lane&15;
  const int qt = blockIdx.x, h = blockIdx.y, b = blockIdx.z;
  const int i0 = qt * 64;
  const size_t bh = (size_t)(b*H_ + h) * LP_ * HD_;
  const u16* qh_b = qh + bh;
  const u16* kh_b = kh + bh;
  const u16* vh_b = vh + bh;

  // phase 0: bias tables pvhb for this block's 64 rows
  for (int o = tid; o < 64*60; o += 256){
    int row = o / 60, bin = o - (o/60)*60;
    const u16* qrow = qh_b + (size_t)(i0 + row) * HD_;
    const float* trow = (bin < 30) ? (tvk + bin*HD_) : (thk + (bin-30)*HD_);
    pvhb[row*66 + bin] = f2b(dotqt(qrow, trow));
  }

  // per-lane row constants (C layout rows: q*4+r)
  int rv_[4], cv_[4], ig_[4];
  #pragma unroll
  for (int r=0;r<4;++r){
    int ig = i0 + w*16 + q*4 + r;
    ig_[r] = ig;
    int ii = ig > 0 ? ig - 1 : 0;
    int dv24 = ii / 24;
    rv_[r] = dv24;
    cv_[r] = ii - dv24*24;
  }

  // Q fragments (A layout: m=lane&15, k=q*8+j)
  bf16x8 aq0 = *(const bf16x8*)(qh_b + (size_t)(i0 + w*16 + c)*HD_ + q*8);
  bf16x8 aq1 = *(const bf16x8*)(qh_b + (size_t)(i0 + w*16 + c)*HD_ + 32 + q*8);

  f32x4 o4[4], hist[4];
  #pragma unroll
  for (int nt=0;nt<4;++nt){ f32x4 z = {0.f,0.f,0.f,0.f}; o4[nt] = z; hist[nt] = z; }
  u16* Ps_w = Ps + w*(16*40);

  __syncthreads();

  // CLS-slot bias values per r
  float pv0[4], ph0[4];
  #pragma unroll
  for (int r=0;r<4;++r){
    int lrow = w*16 + q*4 + r;
    pv0[r] = b2f(pvhb[lrow*66 + 0]);
    ph0[r] = b2f(pvhb[lrow*66 + 30]);
  }

  for (int jt = 0; jt < 19; ++jt){
    int j0 = jt * 32;
    // prefetch indicator B-fragments (same for all blocks; L2-resident)
    uint4 bi_raw[4];
    #pragma unroll
    for (int nt=0;nt<4;++nt) bi_raw[nt] = ((const uint4*)ind)[(jt*4 + nt)*64 + lane];

    __syncthreads();
    { // stage K tile [32][72] and V^T tile [64][40]
      int row = tid >> 3, ch = tid & 7;
      uint4 d4 = *(const uint4*)(kh_b + (size_t)(j0+row)*HD_ + ch*8);
      *(uint4*)(Ks + row*72 + ch*8) = d4;
      int jl = tid & 31, dch = (tid >> 5) * 8;
      uint4 v4 = *(const uint4*)(vh_b + (size_t)(j0+jl)*HD_ + dch);
      u32 vvv[4] = {v4.x, v4.y, v4.z, v4.w};
      #pragma unroll
      for (int e=0;e<4;++e){
        Vts[(dch + 2*e    )*40 + jl] = (u16)(vvv[e] & 0xffffu);
        Vts[(dch + 2*e + 1)*40 + jl] = (u16)(vvv[e] >> 16);
      }
    }
    __syncthreads();

    #pragma unroll
    for (int sub=0; sub<2; ++sub){
      bf16x8 bk0 = *(const bf16x8*)(Ks + (sub*16 + c)*72 + q*8);
      bf16x8 bk1 = *(const bf16x8*)(Ks + (sub*16 + c)*72 + 32 + q*8);
      f32x4 s4 = {0.f,0.f,0.f,0.f};
      s4 = mfma_bf16(aq0, bk0, s4);
      s4 = mfma_bf16(aq1, bk1, s4);

      int jbase = j0 + sub*16;
      int j  = jbase + c;
      bool jv = (j < L_);
      int jj = j - 1;
      int gR  = (j==0) ? 24 : (jj/24);  if (gR > 23 && j != 0) gR = 23;   // gv bin
      int cbR = (j==0) ? 24 : (jj - (jj/24)*24);                          // gh bin
      int sga = (jbase <= 1) ? 0 : ((jbase-1)/24); if (sga > 23) sga = 23;
      int sgb = (jbase + 14) / 24;                 if (sgb > 23) sgb = 23;

      #pragma unroll
      for (int r=0;r<4;++r){
        int lrow = w*16 + q*4 + r;
        int dvlo = sga - rv_[r]; dvlo = dvlo < -14 ? -14 : (dvlo > 14 ? 14 : dvlo);
        int dvhi = sgb - rv_[r]; dvhi = dvhi < -14 ? -14 : (dvhi > 14 ? 14 : dvhi);
        float bvlo = b2f(pvhb[lrow*66 + dvlo + 15]);
        float bvhi = b2f(pvhb[lrow*66 + dvhi + 15]);
        float bv = (gR == sgb) ? bvhi : bvlo;
        int dh = cbR - cv_[r]; dh = dh < -14 ? -14 : (dh > 14 ? 14 : dh);
        float bhh = b2f(pvhb[lrow*66 + dh + 45]);
        bool cls = (j == 0) || (ig_[r] == 0);
        float bias = (cls ? pv0[r] : bv) + (cls ? ph0[r] : bhh);
        float s = s4[r]*SCALE_ + bias;
        s = fminf(fmaxf(s, -80.f), 30.f);           // NaN-proof clamp
        float p = jv ? __expf(s) : 0.f;             // no-max softmax
        Ps_w[(q*4+r)*40 + sub*16 + c] = f2b(p);
      }
    }
    // P·V and P·Ind via LDS round-trip (m120); fence stops TBAA reordering
    lds_fence();
    bf16x8 ap = *(const bf16x8*)(Ps_w + c*40 + q*8);
    #pragma unroll
    for (int nt=0;nt<4;++nt){
      bf16x8 bv2 = *(const bf16x8*)(Vts + (nt*16 + c)*40 + q*8);
      o4[nt] = mfma_bf16(ap, bv2, o4[nt]);
      bf16x8 bI = *(const bf16x8*)&bi_raw[nt];
      hist[nt] = mfma_bf16(ap, bI, hist[nt]);
    }
  }

  // write histogram C-regs to gvh: row=w*16+q*4+r, bin=nt*16+c (each cell one writer)
  #pragma unroll
  for (int nt=0;nt<4;++nt){
    int bin = nt*16 + c;
    if (bin < 50){
      #pragma unroll
      for (int r=0;r<4;++r)
        gvh[(size_t)(w*16 + q*4 + r)*52 + bin] = hist[nt][r];
    }
  }

  __syncthreads();   // hist in gvh; Ks/Vts/Ps/pvhb dead

  // fold histograms into table-space weights W[16 rows][72-padded bins] bf16 (overlay Ks/Vts)
  u16* Wm = (u16*)sb + w*(16*72);
  for (int o = lane; o < 16*72; o += 64) Wm[o] = 0;
  if (lane < 16){
    int lrow = w*16 + lane;
    int ig = i0 + lrow;
    const float* gv = gvh + (size_t)lrow*52;
    u16* wrp = Wm + lane*72;
    if (ig == 0){
      float sv=0.f, sh=0.f;
      for (int g2=0; g2<25; ++g2){ sv += gv[g2]; sh += gv[25+g2]; }
      wrp[0] = f2b(sv); wrp[30] = f2b(sh);
    } else {
      int rr = (ig-1)/24, cc2 = (ig-1) - ((ig-1)/24)*24;
      wrp[0]  = f2b(gv[24]);     // CLS -> table idx 0
      wrp[30] = f2b(gv[49]);
      for (int t=1; t<30; ++t){
        float sv = 0.f, sh = 0.f;
        if (t == 1){
          for (int g2=0; g2 <= rr-14  && g2 < 24; ++g2) sv += gv[g2];
          for (int c2=0; c2 <= cc2-14 && c2 < 24; ++c2) sh += gv[25+c2];
        } else if (t == 29){
          for (int g2 = (rr+14  < 0 ? 0 : rr+14 ); g2 < 24; ++g2) sv += gv[g2];
          for (int c2 = (cc2+14 < 0 ? 0 : cc2+14); c2 < 24; ++c2) sh += gv[25+c2];
        } else {
          int g2 = rr  + t - 15; if (g2 >= 0 && g2 < 24) sv = gv[g2];
          int c2 = cc2 + t - 15; if (c2 >= 0 && c2 < 24) sh = gv[25+c2];
        }
        wrp[t] = f2b(sv); wrp[30+t] = f2b(sh);
      }
    }
  }
  // combined value-table transposed: tabT[d][bin] (overlay Ps+pvhb)
  u16* tabT = (u16*)(sb + 9728);
  for (int o = tid; o < 64*72; o += 256){
    int d2 = o / 72, b2 = o - (o/72)*72;
    float val = 0.f;
    if (b2 < 30)      val = tvv[b2*HD_ + d2];
    else if (b2 < 60) val = thv[(b2-30)*HD_ + d2];
    tabT[d2*72 + b2] = f2b(val);
  }
  __syncthreads();

  // rel-V term: o += W(16x64) @ TabC(64x64)
  bf16x8 aw0 = *(const bf16x8*)(Wm + c*72 + q*8);
  bf16x8 aw1 = *(const bf16x8*)(Wm + c*72 + 32 + q*8);
  #pragma unroll
  for (int nt=0;nt<4;++nt){
    bf16x8 bt0 = *(const bf16x8*)(tabT + (nt*16+c)*72 + q*8);
    bf16x8 bt1 = *(const bf16x8*)(tabT + (nt*16+c)*72 + 32 + q*8);
    o4[nt] = mfma_bf16(aw0, bt0, o4[nt]);
    o4[nt] = mfma_bf16(aw1, bt1, o4[nt]);
  }

  // softmax denominator from histogram row sums (bins 0..24) + store
  u16* oh_b = oh + bh;
  #pragma unroll
  for (int r=0;r<4;++r){
    if (ig_[r] < L_){
      const float* gr = gvh + (size_t)(w*16 + q*4 + r)*52;
      f32x4 a0 = *(const f32x4*)(gr);
      f32x4 a1 = *(const f32x4*)(gr+4);
      f32x4 a2 = *(const f32x4*)(gr+8);
      f32x4 a3 = *(const f32x4*)(gr+12);
      f32x4 a4 = *(const f32x4*)(gr+16);
      f32x4 a5 = *(const f32x4*)(gr+20);
      float lsum = (a0[0]+a0[1]+a0[2]+a0[3]) + (a1[0]+a1[1]+a1[2]+a1[3])
                 + (a2[0]+a2[1]+a2[2]+a2[3]) + (a3[0]+a3[1]+a3[2]+a3[3])
                 + (a4[0]+a4[1]+a4[2]+a4[3]) + (a5[0]+a5[1]+a5[2]+a5[3]) + gr[24];
      float inv = 1.f / lsum;
      #pragma unroll
      for (int nt=0;nt<4;++nt)
        oh_b[(size_t)ig_[r]*HD_ + nt*16 + c] = f2b(o4[nt][r] * inv);
    }
  }
}

// ---------------- launch ----------------
extern "C" void kernel_launch(void* const* d_in, const int* in_sizes, int n_in,
                              void* d_out, int out_size, void* d_ws, size_t ws_size,
                              hipStream_t stream)
{
  (void)in_sizes; (void)n_in; (void)out_size; (void)ws_size;
  const float* q_   = (const float*)d_in[0];
  const float* k_   = (const float*)d_in[1];
  const float* v_   = (const float*)d_in[2];
  const float* Wq_  = (const float*)d_in[3];
  const float* bq_  = (const float*)d_in[4];
  const float* Wk_  = (const float*)d_in[5];
  const float* bk_  = (const float*)d_in[6];
  const float* Wv_  = (const float*)d_in[7];
  const float* bv_  = (const float*)d_in[8];
  const float* Wp_  = (const float*)d_in[9];
  const float* bp_  = (const float*)d_in[10];
  const float* tvk_ = (const float*)d_in[11];
  const float* thk_ = (const float*)d_in[12];
  const float* tvv_ = (const float*)d_in[13];
  const float* thv_ = (const float*)d_in[14];

  char* ws = (char*)d_ws;
  const size_t szHead = (size_t)B_*H_*LP_*HD_*2;   // 31,457,280 B
  const size_t szQKV  = (size_t)M_*D_*2;           // 28,360,704 B
  u16* qh   = (u16*)(ws);
  u16* kh   = (u16*)(ws + szHead);
  u16* vh   = (u16*)(ws + 2*szHead);
  u16* oh   = (u16*)(ws + 3*szHead);   // doubles as q_bf before attn
  u16* q_bf = oh;
  u16* k_bf = (u16*)(ws + 4*szHead);
  u16* v_bf = (u16*)(ws + 4*szHead + szQKV);
  u16* WqT  = (u16*)(ws + 4*szHead + 2*szQKV);
  u16* WkT  = WqT + 768*768;
  u16* WvT  = WkT + 768*768;
  u16* WpT  = WvT + 768*768;
  u16* ind  = WpT + 768*768;           // 77,824 B
  // total ~187.4 MB

  ind_setup<<<19, 256, 0, stream>>>(ind);
  transpose768<<<dim3(24,24,4), 256, 0, stream>>>(Wq_, Wk_, Wv_, Wp_, WqT, WkT, WvT, WpT);
  cvt3_bf16<<<dim3((M_*D_/8 + 255)/256, 3), 256, 0, stream>>>(q_, k_, v_, q_bf, k_bf, v_bf);
  gemm_kernel<<<912, 256, 0, stream>>>(q_bf, WqT, bq_, nullptr, qh, 0);
  gemm_kernel<<<912, 256, 0, stream>>>(k_bf, WkT, bk_, nullptr, kh, 1);
  gemm_kernel<<<912, 256, 0, stream>>>(v_bf, WvT, bv_, nullptr, vh, 2);
  attn_kernel<<<dim3(10,12,32), 256, 0, stream>>>(qh, kh, vh, tvk_, thk_, tvv_, thv_, ind, oh);
  gemm_kernel<<<912, 256, 0, stream>>>(oh, WpT, bp_, q_, d_out, 3);
}